// Round 16
// baseline (233.431 us; speedup 1.0000x reference)
//
#include <hip/hip_runtime.h>
#include <cstdint>
#include <cstddef>

#define EPS_ 1e-5f
// sizes
#define NATOM 16384      // B*N
#define NB    8
#define NN    2048
#define NM    16
#define NHA   64
#define NHB   32
#define NHG   32
#define NVOCAB 100
#define NHINIT 92
#define NAMINO_ 2048
#define NPART 1024       // conv blocks
#define NSLOT 32         // atomic accumulation slots

// ws layout (float offsets)
#define OFF_EMB      0                 // 16384*64   = 1048576
#define OFF_SELF     1048576           // 16384*128 (permuted [atom][l15*8+cb], chan = cb*16+l15)
#define OFF_NBRU     3145728           // 16384*64 uint ([atom][j*4+c2] bf16-pairs (c2*16+j, +64))
#define OFF_S        4194304           // 16384*64   = 1048576
// ---- zeroed region starts here ----
#define OFF_AMINO    5242880           // 2048*64    = 131072
#define OFF_PSUM     5373952           // 8*64 = 512
#define OFF_MSUM     5374464           // 8
#define OFF_MAX      5374472           // 1 (int, holds max(0x7fffffff - k))
#define OFF_SLOT1    5374480           // 4 layers * 32 slots * 256 = 32768
#define OFF_SLOT2    5407248           // 4 layers * 32 slots * 128 = 16384
#define ZERO_FLOATS  (5423632 - 5242880)
// ---- zeroed region ends ----
#define OFF_PACK     5423632           // 16384*64 uint4 = 4194304 floats
#define OFF_WPACK    9617936           // 4*8*64 uint4 = 8192 floats (conv W_e frags)
#define OFF_WPACK2   9626128           // 4*32*64 uint4 = 32768 floats (proj W frags)
#define OFF_T        9658896           // 100*64 = 6400 (embed table)
#define WS_FLOATS    9665296

typedef __attribute__((ext_vector_type(8))) short bf16x8;
typedef __attribute__((ext_vector_type(4))) float f32x4;

static __device__ __forceinline__ short f2bf(float f) {
    union { float f; uint32_t u; } v; v.f = f;
    uint32_t r = v.u + 0x7fffu + ((v.u >> 16) & 1u);   // RNE
    return (short)(r >> 16);
}
static __device__ __forceinline__ float bfLo(uint32_t x) {
    union { uint32_t u; float f; } v; v.u = x << 16; return v.f;
}
static __device__ __forceinline__ float bfHi(uint32_t x) {
    union { uint32_t u; float f; } v; v.u = x & 0xffff0000u; return v.f;
}

// XCD-batch-affinity swizzle: XCD x (= bid&7) handles only batch x.
static __device__ __forceinline__ int conv_wg(int bid) {
    return (bid & 7) * (NPART / 8) + (bid >> 3);
}

// ---------------- table (blocks 0..24) + zero accumulators (blocks 25..) -------------
__launch_bounds__(256)
__global__ void k_table(const float* __restrict__ et, const float* __restrict__ W,
                        const float* __restrict__ b, float* __restrict__ T,
                        float* __restrict__ zbase)
{
    const int t = threadIdx.x;
    if (blockIdx.x < 25) {
        int v = blockIdx.x * 4 + (t >> 6), c = t & 63;
        float acc = b[c];
        for (int h = 0; h < NHINIT; ++h)
            acc = fmaf(et[v * NHINIT + h], W[h * NHA + c], acc);
        T[v * NHA + c] = acc;
        return;
    }
    int idx = (blockIdx.x - 25) * 256 + t;
    if (idx < ZERO_FLOATS) zbase[idx] = 0.f;
}

// ---------------- prep ----------------
// blocks 0..4095:     pack nbr_emb -> bf16 MFMA A-frags
// blocks 4096..5119:  embed gather emb[atom] = T[idx[atom]]
// blocks 5120..5123:  pre-pack W_e conv B-frags (layer = blockIdx-5120)
// blocks 5124..5127:  pre-pack proj W B-frags (layer = blockIdx-5124)
__launch_bounds__(256)
__global__ void k_prep(const float* __restrict__ nbr_emb, uint4* __restrict__ pack,
                       const int* __restrict__ atom_idx, const float* __restrict__ T,
                       float* __restrict__ emb,
                       const float* __restrict__ fcW, uint4* __restrict__ wpack,
                       uint4* __restrict__ wpack2)
{
    const int t = threadIdx.x;
    if (blockIdx.x < 4096) {
        int g = blockIdx.x * 256 + t;        // over 16384*64
        int bn = g >> 6, l = g & 63;
        const float* src = nbr_emb + (size_t)bn * 512 + (l & 15) * 32 + (l >> 4) * 8;
        float4 a = *reinterpret_cast<const float4*>(src);
        float4 b = *reinterpret_cast<const float4*>(src + 4);
        union { short s[8]; uint4 u; } o;
        o.s[0] = f2bf(a.x); o.s[1] = f2bf(a.y); o.s[2] = f2bf(a.z); o.s[3] = f2bf(a.w);
        o.s[4] = f2bf(b.x); o.s[5] = f2bf(b.y); o.s[6] = f2bf(b.z); o.s[7] = f2bf(b.w);
        pack[g] = o.u;
        return;
    }
    if (blockIdx.x >= 5124) {
        // proj W B-frags for one layer: f = h*16 + ks*8 + cb
        int L = blockIdx.x - 5124;
        if (t < 64) {
            const float* WL = fcW + (size_t)L * 160 * 128;
            for (int f = 0; f < 32; ++f) {
                int h = f >> 4, ks = (f >> 3) & 1, cb = f & 7;
                union { short s[8]; uint4 u; } w;
#pragma unroll
                for (int j = 0; j < 8; ++j)
                    w.s[j] = f2bf(WL[(h * 64 + ks * 32 + (t >> 4) * 8 + j) * 128
                                     + cb * 16 + (t & 15)]);
                wpack2[L * 2048 + f * 64 + t] = w.u;
            }
        }
        return;
    }
    if (blockIdx.x >= 5120) {
        // conv W_e B-frags for one layer
        int L = blockIdx.x - 5120;
        if (t < 64) {
            int l15 = t & 15, lg = t >> 4;
            const float* We = fcW + (size_t)L * 160 * 128 + 128 * 128;
#pragma unroll
            for (int cb = 0; cb < 8; ++cb) {
                union { short s[8]; uint4 u; } w;
#pragma unroll
                for (int j = 0; j < 8; ++j)
                    w.s[j] = f2bf(We[(lg * 8 + j) * 128 + cb * 16 + l15]);
                wpack[L * 512 + cb * 64 + t] = w.u;
            }
        }
        return;
    }
    // embed gather: 1024 blocks over 262144 float4s (16 float4 per atom)
    {
        int g2 = (blockIdx.x - 4096) * 256 + t;
        int atom = g2 >> 4, c4 = g2 & 15;
        int idx = atom_idx[atom];
        reinterpret_cast<float4*>(emb)[g2] =
            reinterpret_cast<const float4*>(T)[idx * 16 + c4];
    }
}

// ---------------- per-atom projections via MFMA (+ fused BN2 finalize & update) ------
// block = 16 atoms; wave w computes colblocks {w, w+4} for self AND nbr halves.
template<int UPD>
__launch_bounds__(256)
__global__ void k_proj(float* __restrict__ emb, const float* __restrict__ mask,
                       const float* __restrict__ s_buf, const float* __restrict__ slot2,
                       const float* __restrict__ g1, const float* __restrict__ b1,
                       const uint4* __restrict__ wp, const float* __restrict__ fcb,
                       float* __restrict__ selfp, uint32_t* __restrict__ nbrpU)
{
    __shared__ __align__(16) unsigned short lexb[16][72];   // padded: stride 144B
    __shared__ float affA[64], affB[64];
    const int t = threadIdx.x;
    if (UPD) {
        if (t < 64) {
            float S = 0.f, Q = 0.f;
#pragma unroll
            for (int s = 0; s < NSLOT; ++s) {
                S += slot2[s * 128 + t];
                Q += slot2[s * 128 + 64 + t];
            }
            float mean = S * (1.f / 16384.f);
            float var = Q * (1.f / 16384.f) - mean * mean;
            float a = g1[t] * rsqrtf(var + EPS_);
            affA[t] = a; affB[t] = b1[t] - mean * a;
        }
        __syncthreads();
    }
    // update + mask + bf16 A-tile
#pragma unroll
    for (int k = 0; k < 4; ++k) {
        int idx = t + k * 256;                 // over 16 atoms x 64 ch
        int a = idx >> 6, c = idx & 63;
        int gi = blockIdx.x * 1024 + idx;
        int atom = blockIdx.x * 16 + a;
        float m = mask[atom];
        float v;
        if (UPD) {
            v = fmaxf(fmaf(s_buf[gi], affA[c], affB[c]) + emb[gi] * m, 0.f);
            emb[gi] = v;
        } else {
            v = emb[gi];
        }
        lexb[a][c] = (unsigned short)f2bf(v * m);
    }
    __syncthreads();
    const int lane = t & 63, w = t >> 6;
    const int l15 = lane & 15, lg = lane >> 4;
    // A-frags (k 0..31 / 32..63)
    const unsigned short* ap = &lexb[l15][lg * 8];
    union { uint4 u; bf16x8 v; } a0, a1;
    a0.u = *reinterpret_cast<const uint4*>(ap);
    a1.u = *reinterpret_cast<const uint4*>(ap + 32);
    // B-frags: f = h*16 + ks*8 + cb, cb in {w, w+4}
    union { uint4 u; bf16x8 v; } B[2][2][2];   // [h][cbi][ks]
#pragma unroll
    for (int h = 0; h < 2; ++h)
#pragma unroll
        for (int cbi = 0; cbi < 2; ++cbi)
#pragma unroll
            for (int ks = 0; ks < 2; ++ks)
                B[h][cbi][ks].u = wp[(h * 16 + ks * 8 + (w + cbi * 4)) * 64 + lane];
    float bias0 = fcb[w * 16 + l15];
    float bias4 = fcb[(w + 4) * 16 + l15];
    f32x4 aS0 = {bias0, bias0, bias0, bias0};
    f32x4 aS4 = {bias4, bias4, bias4, bias4};
    f32x4 aN0 = {0.f, 0.f, 0.f, 0.f};
    f32x4 aN4 = {0.f, 0.f, 0.f, 0.f};
    aS0 = __builtin_amdgcn_mfma_f32_16x16x32_bf16(a0.v, B[0][0][0].v, aS0, 0, 0, 0);
    aS0 = __builtin_amdgcn_mfma_f32_16x16x32_bf16(a1.v, B[0][0][1].v, aS0, 0, 0, 0);
    aS4 = __builtin_amdgcn_mfma_f32_16x16x32_bf16(a0.v, B[0][1][0].v, aS4, 0, 0, 0);
    aS4 = __builtin_amdgcn_mfma_f32_16x16x32_bf16(a1.v, B[0][1][1].v, aS4, 0, 0, 0);
    aN0 = __builtin_amdgcn_mfma_f32_16x16x32_bf16(a0.v, B[1][0][0].v, aN0, 0, 0, 0);
    aN0 = __builtin_amdgcn_mfma_f32_16x16x32_bf16(a1.v, B[1][0][1].v, aN0, 0, 0, 0);
    aN4 = __builtin_amdgcn_mfma_f32_16x16x32_bf16(a0.v, B[1][1][0].v, aN4, 0, 0, 0);
    aN4 = __builtin_amdgcn_mfma_f32_16x16x32_bf16(a1.v, B[1][1][1].v, aN4, 0, 0, 0);
    // stores: C row = atom-in-tile = lg*4+r, col = cb*16+l15
#pragma unroll
    for (int r = 0; r < 4; ++r) {
        size_t atomg = (size_t)blockIdx.x * 16 + lg * 4 + r;
        selfp[atomg * 128 + l15 * 8 + w] = aS0[r];
        selfp[atomg * 128 + l15 * 8 + w + 4] = aS4[r];
        uint32_t lo = (uint16_t)f2bf(aN0[r]);
        uint32_t hi = (uint16_t)f2bf(aN4[r]);
        nbrpU[atomg * 64 + l15 * 4 + w] = lo | (hi << 16);
    }
}

// ---------------- conv pass 1: z stats (MFMA e-term) -> atomic slots ---------------
__launch_bounds__(256, 4)
__global__ void k_conv_stats(const float* __restrict__ selfp, const uint32_t* __restrict__ nbrpU,
                             const uint4* __restrict__ pack, const int* __restrict__ adj,
                             const float* __restrict__ mask, const uint4* __restrict__ wpack,
                             float* __restrict__ slot1)
{
    __shared__ float red[4][256];
    const int lane = threadIdx.x & 63;
    const int wid = threadIdx.x >> 6;
    const int l15 = lane & 15, lg = lane >> 4;
    bf16x8 Wb[8];
#pragma unroll
    for (int cb = 0; cb < 8; ++cb) {
        union { uint4 u; bf16x8 v; } w;
        w.u = wpack[cb * 64 + lane];
        Wb[cb] = w.v;
    }
    float sum[8] = {0, 0, 0, 0, 0, 0, 0, 0};
    float sq[8] = {0, 0, 0, 0, 0, 0, 0, 0};
    const int wg = conv_wg(blockIdx.x);
    const int base = (wg * 4 + wid) * 4;
    const int adjv = adj[base * 16 + lane];    // all 4 atoms' neighbors in one load
    const int b = base >> 11;                  // same batch for all 4 atoms
    const uint32_t* npb = nbrpU + (size_t)b * NN * 64;
#pragma unroll
    for (int aa = 0; aa < 4; ++aa) {
        const int bn = base + aa;
        const float mn = mask[bn];
        union { uint4 u; bf16x8 v; } af;
        af.u = pack[(size_t)bn * 64 + lane];
        const float4* spp = reinterpret_cast<const float4*>(selfp + (size_t)bn * 128 + l15 * 8);
        float4 sA = spp[0], sB = spp[1];
        f32x4 acc[8];
#pragma unroll
        for (int r = 0; r < 4; ++r) {
            const int am = __shfl(adjv, aa * 16 + lg * 4 + r);
            const uint4 u4 = *reinterpret_cast<const uint4*>(npb + (size_t)am * 64 + l15 * 4);
            acc[0][r] = fmaf(mn, bfLo(u4.x), sA.x); acc[4][r] = fmaf(mn, bfHi(u4.x), sB.x);
            acc[1][r] = fmaf(mn, bfLo(u4.y), sA.y); acc[5][r] = fmaf(mn, bfHi(u4.y), sB.y);
            acc[2][r] = fmaf(mn, bfLo(u4.z), sA.z); acc[6][r] = fmaf(mn, bfHi(u4.z), sB.z);
            acc[3][r] = fmaf(mn, bfLo(u4.w), sA.w); acc[7][r] = fmaf(mn, bfHi(u4.w), sB.w);
        }
#pragma unroll
        for (int cb = 0; cb < 8; ++cb)
            acc[cb] = __builtin_amdgcn_mfma_f32_16x16x32_bf16(af.v, Wb[cb], acc[cb], 0, 0, 0);
#pragma unroll
        for (int cb = 0; cb < 8; ++cb) {
#pragma unroll
            for (int r = 0; r < 4; ++r) {
                float z = acc[cb][r];
                sum[cb] += z; sq[cb] = fmaf(z, z, sq[cb]);
            }
        }
    }
#pragma unroll
    for (int cb = 0; cb < 8; ++cb) {
        sum[cb] += __shfl_xor(sum[cb], 16);
        sum[cb] += __shfl_xor(sum[cb], 32);
        sq[cb] += __shfl_xor(sq[cb], 16);
        sq[cb] += __shfl_xor(sq[cb], 32);
    }
    if (lane < 16) {
#pragma unroll
        for (int cb = 0; cb < 8; ++cb) {
            red[wid][cb * 16 + lane] = sum[cb];
            red[wid][128 + cb * 16 + lane] = sq[cb];
        }
    }
    __syncthreads();
    const int t = threadIdx.x;
    float v = red[0][t] + red[1][t] + red[2][t] + red[3][t];
    atomicAdd(&slot1[(blockIdx.x & (NSLOT - 1)) * 256 + t], v);
}

// ---------------- conv pass 2: BN1 finalize + gate + s stats -> atomic slots -------
__launch_bounds__(256, 4)
__global__ void k_conv_gate(const float* __restrict__ selfp, const uint32_t* __restrict__ nbrpU,
                            const uint4* __restrict__ pack, const int* __restrict__ adj,
                            const float* __restrict__ mask, const uint4* __restrict__ wpack,
                            const float* __restrict__ slot1,
                            const float* __restrict__ g0, const float* __restrict__ b0,
                            float* __restrict__ s_out, float* __restrict__ slot2)
{
    __shared__ float red[4][128];
    __shared__ float a1[128], b1s[128];
    const int t = threadIdx.x;
    if (t < 128) {
        float S = 0.f, Q = 0.f;
#pragma unroll
        for (int s = 0; s < NSLOT; ++s) {
            S += slot1[s * 256 + t];
            Q += slot1[s * 256 + 128 + t];
        }
        float mean = S * (1.f / 262144.f);
        float var = Q * (1.f / 262144.f) - mean * mean;
        float a = g0[t] * rsqrtf(var + EPS_);
        a1[t] = a; b1s[t] = b0[t] - mean * a;
    }
    __syncthreads();
    const int lane = threadIdx.x & 63;
    const int wid = threadIdx.x >> 6;
    const int l15 = lane & 15, lg = lane >> 4;
    bf16x8 Wb[8];
#pragma unroll
    for (int cb = 0; cb < 8; ++cb) {
        union { uint4 u; bf16x8 v; } w;
        w.u = wpack[cb * 64 + lane];
        Wb[cb] = w.v;
    }
    float aA[8], aB[8];
#pragma unroll
    for (int cb = 0; cb < 8; ++cb) {
        aA[cb] = a1[cb * 16 + l15];
        aB[cb] = b1s[cb * 16 + l15];
    }
    float ssum[4] = {0, 0, 0, 0}, ssq[4] = {0, 0, 0, 0};
    const int wg = conv_wg(blockIdx.x);
    const int base = (wg * 4 + wid) * 4;
    const int adjv = adj[base * 16 + lane];
    const int b = base >> 11;
    const uint32_t* npb = nbrpU + (size_t)b * NN * 64;
#pragma unroll
    for (int aa = 0; aa < 4; ++aa) {
        const int bn = base + aa;
        const float mn = mask[bn];
        union { uint4 u; bf16x8 v; } af;
        af.u = pack[(size_t)bn * 64 + lane];
        const float4* spp = reinterpret_cast<const float4*>(selfp + (size_t)bn * 128 + l15 * 8);
        float4 sA = spp[0], sB = spp[1];
        f32x4 acc[8];
#pragma unroll
        for (int r = 0; r < 4; ++r) {
            const int am = __shfl(adjv, aa * 16 + lg * 4 + r);
            const uint4 u4 = *reinterpret_cast<const uint4*>(npb + (size_t)am * 64 + l15 * 4);
            acc[0][r] = fmaf(mn, bfLo(u4.x), sA.x); acc[4][r] = fmaf(mn, bfHi(u4.x), sB.x);
            acc[1][r] = fmaf(mn, bfLo(u4.y), sA.y); acc[5][r] = fmaf(mn, bfHi(u4.y), sB.y);
            acc[2][r] = fmaf(mn, bfLo(u4.z), sA.z); acc[6][r] = fmaf(mn, bfHi(u4.z), sB.z);
            acc[3][r] = fmaf(mn, bfLo(u4.w), sA.w); acc[7][r] = fmaf(mn, bfHi(u4.w), sB.w);
        }
#pragma unroll
        for (int cb = 0; cb < 8; ++cb)
            acc[cb] = __builtin_amdgcn_mfma_f32_16x16x32_bf16(af.v, Wb[cb], acc[cb], 0, 0, 0);
        float sv[4];
#pragma unroll
        for (int cb = 0; cb < 4; ++cb) {
            float s = 0.f;
#pragma unroll
            for (int r = 0; r < 4; ++r) {
                float zf = fmaf(acc[cb][r], aA[cb], aB[cb]);
                float zc = fmaf(acc[cb + 4][r], aA[cb + 4], aB[cb + 4]);
                float f = 1.f / (1.f + __expf(-zf));
                s = fmaf(f, fmaxf(zc, 0.f), s);
            }
            s += __shfl_xor(s, 16);
            s += __shfl_xor(s, 32);
            sv[cb] = s;
            ssum[cb] += s; ssq[cb] = fmaf(s, s, ssq[cb]);
        }
        if (lane < 16) {
#pragma unroll
            for (int cb = 0; cb < 4; ++cb)
                s_out[(size_t)bn * 64 + cb * 16 + lane] = sv[cb];
        }
    }
    if (lane < 16) {
#pragma unroll
        for (int cb = 0; cb < 4; ++cb) {
            red[wid][cb * 16 + lane] = ssum[cb];
            red[wid][64 + cb * 16 + lane] = ssq[cb];
        }
    }
    __syncthreads();
    if (t < 128) {
        float v = red[0][t] + red[1][t] + red[2][t] + red[3][t];
        atomicAdd(&slot2[(blockIdx.x & (NSLOT - 1)) * 128 + t], v);
    }
}

// ---------------- pooling (+ fused BN2 finalize & final update) ----------------
__launch_bounds__(256)
__global__ void k_pool(const float* __restrict__ emb, const float* __restrict__ s_buf,
                       const float* __restrict__ slot2,
                       const float* __restrict__ g1, const float* __restrict__ b1,
                       const float* __restrict__ mask, const int* __restrict__ aidx,
                       float* __restrict__ amino, float* __restrict__ psum,
                       float* __restrict__ msum, int* __restrict__ maxv)
{
    __shared__ float red[256];
    __shared__ float mred[4];
    __shared__ int kred[4];
    __shared__ float affA[64], affB[64];
    int t = threadIdx.x, sub = t >> 6, c = t & 63;
    if (t < 64) {
        float S = 0.f, Q = 0.f;
#pragma unroll
        for (int s = 0; s < NSLOT; ++s) {
            S += slot2[s * 128 + t];
            Q += slot2[s * 128 + 64 + t];
        }
        float mean = S * (1.f / 16384.f);
        float var = Q * (1.f / 16384.f) - mean * mean;
        float a = g1[t] * rsqrtf(var + EPS_);
        affA[t] = a; affB[t] = b1[t] - mean * a;
    }
    __syncthreads();
    int base = blockIdx.x * 32;
    int b = base >> 11;
    float pacc = 0.f, macc = 0.f;
    int kmax = 0;    // holds 0x7fffffff - kmin
    for (int j = 0; j < 8; ++j) {
        int bn = base + sub + 4 * j;
        size_t gi = (size_t)bn * 64 + c;
        float m = mask[bn];
        float e4 = fmaxf(fmaf(s_buf[gi], affA[c], affB[c]) + emb[gi] * m, 0.f);
        float v = e4 * m;
        int k = aidx[bn];
        atomicAdd(&amino[(size_t)k * 64 + c], v);
        pacc += v;
        if (c == 0) { macc += m; kmax = max(kmax, 0x7fffffff - k); }
    }
    red[t] = pacc;
    if (c == 0) { mred[sub] = macc; kred[sub] = kmax; }
    __syncthreads();
    if (t < 64) {
        float tot = red[t] + red[64 + t] + red[128 + t] + red[192 + t];
        atomicAdd(&psum[b * 64 + t], tot);
    }
    if (t == 0) {
        atomicAdd(&msum[b], mred[0] + mred[1] + mred[2] + mred[3]);
        atomicMax(maxv, max(max(kred[0], kred[1]), max(kred[2], kred[3])));
    }
}

// ---------------- heads: amino (blocks 0..255), protein (256), maskpooled (257..264) --
__launch_bounds__(256)
__global__ void k_heads(const float* __restrict__ amino, const float* __restrict__ W_af,
                        const float* __restrict__ b_af, const float* __restrict__ W_ao,
                        const float* __restrict__ b_ao,
                        const float* __restrict__ psum, const float* __restrict__ msum,
                        const float* __restrict__ W_cf, const float* __restrict__ b_cf,
                        const float* __restrict__ W_out, const float* __restrict__ b_out,
                        const int* __restrict__ maxv, float* __restrict__ out)
{
    const int t = threadIdx.x;
    if (blockIdx.x < 256) {
        int kk = t >> 5, j = t & 31;
        int k = blockIdx.x * 8 + kk;
        float acc = b_af[j];
        for (int c = 0; c < 64; ++c)
            acc = fmaf(fmaxf(amino[(size_t)k * 64 + c], 0.f), W_af[c * 32 + j], acc);
        float h = fmaxf(acc, 0.f);
        float val = h * W_ao[j];
        for (int off = 16; off > 0; off >>= 1) val += __shfl_down(val, off, 32);
        if (j == 0) out[8 + k] = val + b_ao[0];
    } else if (blockIdx.x == 256) {
        int bb = t >> 5, j = t & 31;
        float inv = 1.f / msum[bb];
        float acc = b_cf[j];
        for (int c = 0; c < 64; ++c)
            acc = fmaf(fmaxf(psum[bb * 64 + c] * inv, 0.f), W_cf[c * 32 + j], acc);
        float h = fmaxf(acc, 0.f);
        float val = h * W_out[j];
        for (int off = 16; off > 0; off >>= 1) val += __shfl_down(val, off, 32);
        if (j == 0) out[bb] = val + b_out[0];
    } else {
        int k = (blockIdx.x - 257) * 256 + t;
        int minv = 0x7fffffff - *maxv;
        out[8 + NAMINO_ + k] = (k < minv) ? 0.f : 1.f;
    }
}

// ---------------- launch ----------------
extern "C" void kernel_launch(void* const* d_in, const int* in_sizes, int n_in,
                              void* d_out, int out_size, void* d_ws, size_t ws_size,
                              hipStream_t stream)
{
    const int* atom_idx = (const int*)d_in[0];
    const float* nbr_emb = (const float*)d_in[1];
    const int* adj = (const int*)d_in[2];
    const int* aidx = (const int*)d_in[3];
    const float* mask = (const float*)d_in[4];
    const float* et = (const float*)d_in[5];
    const float* W_emb = (const float*)d_in[6];
    const float* b_emb = (const float*)d_in[7];
    const float* fcW = (const float*)d_in[8];
    const float* fcb = (const float*)d_in[9];
    const float* bnh_g = (const float*)d_in[10];
    const float* bnh_b = (const float*)d_in[11];
    const float* bno_g = (const float*)d_in[12];
    const float* bno_b = (const float*)d_in[13];
    const float* W_cf = (const float*)d_in[14];
    const float* b_cf = (const float*)d_in[15];
    const float* W_out = (const float*)d_in[16];
    const float* b_out = (const float*)d_in[17];
    const float* W_af = (const float*)d_in[18];
    const float* b_af = (const float*)d_in[19];
    const float* W_ao = (const float*)d_in[20];
    const float* b_ao = (const float*)d_in[21];

    float* ws = (float*)d_ws;
    float* emb = ws + OFF_EMB;
    float* selfp = ws + OFF_SELF;
    uint32_t* nbrpU = (uint32_t*)(ws + OFF_NBRU);
    float* s_buf = ws + OFF_S;
    float* amino = ws + OFF_AMINO;
    float* psum = ws + OFF_PSUM;
    float* msum = ws + OFF_MSUM;
    int* maxv = (int*)(ws + OFF_MAX);
    float* slot1 = ws + OFF_SLOT1;
    float* slot2 = ws + OFF_SLOT2;
    uint4* pack = (uint4*)(ws + OFF_PACK);
    uint4* wpack = (uint4*)(ws + OFF_WPACK);
    uint4* wpack2 = (uint4*)(ws + OFF_WPACK2);
    float* T = ws + OFF_T;
    float* out = (float*)d_out;

    // k_table also zeroes amino + psum + msum + maxv + all BN slots (blocks >= 25)
    k_table<<<25 + (ZERO_FLOATS + 255) / 256, 256, 0, stream>>>(et, W_emb, b_emb, T, amino);
    k_prep<<<5128, 256, 0, stream>>>(nbr_emb, pack, atom_idx, T, emb,
                                     fcW, wpack, wpack2);

    for (int i = 0; i < 4; ++i) {
        const uint4* wp2 = wpack2 + (size_t)i * 2048;
        if (i == 0)
            k_proj<0><<<NATOM / 16, 256, 0, stream>>>(emb, mask, s_buf, slot2, bno_g, bno_b,
                                                      wp2, fcb + i * 128, selfp, nbrpU);
        else
            k_proj<1><<<NATOM / 16, 256, 0, stream>>>(emb, mask, s_buf,
                                                      slot2 + (size_t)(i - 1) * (NSLOT * 128),
                                                      bno_g + (i - 1) * 64, bno_b + (i - 1) * 64,
                                                      wp2, fcb + i * 128, selfp, nbrpU);
        k_conv_stats<<<NPART, 256, 0, stream>>>(selfp, nbrpU, pack, adj, mask,
                                                wpack + (size_t)i * 512,
                                                slot1 + (size_t)i * (NSLOT * 256));
        k_conv_gate<<<NPART, 256, 0, stream>>>(selfp, nbrpU, pack, adj, mask,
                                               wpack + (size_t)i * 512,
                                               slot1 + (size_t)i * (NSLOT * 256),
                                               bnh_g + i * 128, bnh_b + i * 128,
                                               s_buf, slot2 + (size_t)i * (NSLOT * 128));
    }

    k_pool<<<NATOM / 32, 256, 0, stream>>>(emb, s_buf, slot2 + 3 * (NSLOT * 128),
                                           bno_g + 3 * 64, bno_b + 3 * 64,
                                           mask, aidx, amino, psum, msum, maxv);
    k_heads<<<265, 256, 0, stream>>>(amino, W_af, b_af, W_ao, b_ao,
                                     psum, msum, W_cf, b_cf, W_out, b_out, maxv, out);
}

// Round 17
// 223.195 us; speedup vs baseline: 1.0459x; 1.0459x over previous
//
#include <hip/hip_runtime.h>
#include <cstdint>
#include <cstddef>

#define EPS_ 1e-5f
// sizes
#define NATOM 16384      // B*N
#define NB    8
#define NN    2048
#define NM    16
#define NHA   64
#define NHB   32
#define NHG   32
#define NVOCAB 100
#define NHINIT 92
#define NAMINO_ 2048
#define NPART 1024       // conv blocks
#define NSLOT 8          // atomic accumulation slots

// ws layout (float offsets)
#define OFF_EMB      0                 // 16384*64   = 1048576
#define OFF_SELF     1048576           // 16384*128 (permuted [atom][l15*8+cb], chan = cb*16+l15)
#define OFF_NBRU     3145728           // 16384*64 uint ([atom][j*4+c2] bf16-pairs (c2*16+j, +64))
#define OFF_S        4194304           // 16384*64   = 1048576
// ---- zeroed region starts here ----
#define OFF_AMINO    5242880           // 2048*64    = 131072
#define OFF_PSUM     5373952           // 8*64 = 512
#define OFF_MSUM     5374464           // 8
#define OFF_MAX      5374472           // 1 (int, holds max(0x7fffffff - k))
#define OFF_SLOT1    5374480           // 4 layers * 8 slots * 256 = 8192
#define OFF_SLOT2    5382672           // 4 layers * 8 slots * 128 = 4096
#define ZERO_FLOATS  (5386768 - 5242880)   // 143888
// ---- zeroed region ends ----
#define OFF_PACK     5386768           // 16384*64 uint4 = 4194304 floats
#define OFF_WPACK    9581072           // 4*8*64 uint4 = 8192 floats (conv W_e frags)
#define OFF_WPACK2   9589264           // 4*32*64 uint4 = 32768 floats (proj W frags)
#define OFF_T        9622032           // 100*64 = 6400 (embed table)
#define WS_FLOATS    9628432

typedef __attribute__((ext_vector_type(8))) short bf16x8;
typedef __attribute__((ext_vector_type(4))) float f32x4;

static __device__ __forceinline__ short f2bf(float f) {
    union { float f; uint32_t u; } v; v.f = f;
    uint32_t r = v.u + 0x7fffu + ((v.u >> 16) & 1u);   // RNE
    return (short)(r >> 16);
}
static __device__ __forceinline__ float bfLo(uint32_t x) {
    union { uint32_t u; float f; } v; v.u = x << 16; return v.f;
}
static __device__ __forceinline__ float bfHi(uint32_t x) {
    union { uint32_t u; float f; } v; v.u = x & 0xffff0000u; return v.f;
}

// XCD-batch-affinity swizzle: XCD x (= bid&7) handles only batch x.
static __device__ __forceinline__ int conv_wg(int bid) {
    return (bid & 7) * (NPART / 8) + (bid >> 3);
}

// ---------------- table (blocks 0..24) + zero accumulators (blocks 25..) -------------
__launch_bounds__(256)
__global__ void k_table(const float* __restrict__ et, const float* __restrict__ W,
                        const float* __restrict__ b, float* __restrict__ T,
                        float* __restrict__ zbase)
{
    const int t = threadIdx.x;
    if (blockIdx.x < 25) {
        int v = blockIdx.x * 4 + (t >> 6), c = t & 63;
        float acc = b[c];
        for (int h = 0; h < NHINIT; ++h)
            acc = fmaf(et[v * NHINIT + h], W[h * NHA + c], acc);
        T[v * NHA + c] = acc;
        return;
    }
    int idx = (blockIdx.x - 25) * 256 + t;
    if (idx < ZERO_FLOATS) zbase[idx] = 0.f;
}

// ---------------- prep ----------------
// blocks 0..4095:     pack nbr_emb -> bf16 MFMA A-frags
// blocks 4096..5119:  embed gather emb[atom] = T[idx[atom]]
// blocks 5120..5123:  pre-pack W_e conv B-frags (layer = blockIdx-5120)
// blocks 5124..5127:  pre-pack proj W B-frags (layer = blockIdx-5124)
__launch_bounds__(256)
__global__ void k_prep(const float* __restrict__ nbr_emb, uint4* __restrict__ pack,
                       const int* __restrict__ atom_idx, const float* __restrict__ T,
                       float* __restrict__ emb,
                       const float* __restrict__ fcW, uint4* __restrict__ wpack,
                       uint4* __restrict__ wpack2)
{
    const int t = threadIdx.x;
    if (blockIdx.x < 4096) {
        int g = blockIdx.x * 256 + t;        // over 16384*64
        int bn = g >> 6, l = g & 63;
        const float* src = nbr_emb + (size_t)bn * 512 + (l & 15) * 32 + (l >> 4) * 8;
        float4 a = *reinterpret_cast<const float4*>(src);
        float4 b = *reinterpret_cast<const float4*>(src + 4);
        union { short s[8]; uint4 u; } o;
        o.s[0] = f2bf(a.x); o.s[1] = f2bf(a.y); o.s[2] = f2bf(a.z); o.s[3] = f2bf(a.w);
        o.s[4] = f2bf(b.x); o.s[5] = f2bf(b.y); o.s[6] = f2bf(b.z); o.s[7] = f2bf(b.w);
        pack[g] = o.u;
        return;
    }
    if (blockIdx.x >= 5124) {
        // proj W B-frags for one layer: f = h*16 + ks*8 + cb
        int L = blockIdx.x - 5124;
        if (t < 64) {
            const float* WL = fcW + (size_t)L * 160 * 128;
            for (int f = 0; f < 32; ++f) {
                int h = f >> 4, ks = (f >> 3) & 1, cb = f & 7;
                union { short s[8]; uint4 u; } w;
#pragma unroll
                for (int j = 0; j < 8; ++j)
                    w.s[j] = f2bf(WL[(h * 64 + ks * 32 + (t >> 4) * 8 + j) * 128
                                     + cb * 16 + (t & 15)]);
                wpack2[L * 2048 + f * 64 + t] = w.u;
            }
        }
        return;
    }
    if (blockIdx.x >= 5120) {
        // conv W_e B-frags for one layer
        int L = blockIdx.x - 5120;
        if (t < 64) {
            int l15 = t & 15, lg = t >> 4;
            const float* We = fcW + (size_t)L * 160 * 128 + 128 * 128;
#pragma unroll
            for (int cb = 0; cb < 8; ++cb) {
                union { short s[8]; uint4 u; } w;
#pragma unroll
                for (int j = 0; j < 8; ++j)
                    w.s[j] = f2bf(We[(lg * 8 + j) * 128 + cb * 16 + l15]);
                wpack[L * 512 + cb * 64 + t] = w.u;
            }
        }
        return;
    }
    // embed gather: 1024 blocks over 262144 float4s (16 float4 per atom)
    {
        int g2 = (blockIdx.x - 4096) * 256 + t;
        int atom = g2 >> 4, c4 = g2 & 15;
        int idx = atom_idx[atom];
        reinterpret_cast<float4*>(emb)[g2] =
            reinterpret_cast<const float4*>(T)[idx * 16 + c4];
    }
}

// ---------------- per-atom projections via MFMA (+ fused BN2 finalize & update) ------
// block = 16 atoms; wave w computes colblocks {w, w+4} for self AND nbr halves.
template<int UPD>
__launch_bounds__(256)
__global__ void k_proj(float* __restrict__ emb, const float* __restrict__ mask,
                       const float* __restrict__ s_buf, const float* __restrict__ slot2,
                       const float* __restrict__ g1, const float* __restrict__ b1,
                       const uint4* __restrict__ wp, const float* __restrict__ fcb,
                       float* __restrict__ selfp, uint32_t* __restrict__ nbrpU)
{
    __shared__ __align__(16) unsigned short lexb[16][72];   // padded: stride 144B
    __shared__ float affA[64], affB[64];
    const int t = threadIdx.x;
    if (UPD) {
        if (t < 64) {
            float S = 0.f, Q = 0.f;
#pragma unroll
            for (int s = 0; s < NSLOT; ++s) {
                S += slot2[s * 128 + t];
                Q += slot2[s * 128 + 64 + t];
            }
            float mean = S * (1.f / 16384.f);
            float var = Q * (1.f / 16384.f) - mean * mean;
            float a = g1[t] * rsqrtf(var + EPS_);
            affA[t] = a; affB[t] = b1[t] - mean * a;
        }
        __syncthreads();
    }
    // update + mask + bf16 A-tile
#pragma unroll
    for (int k = 0; k < 4; ++k) {
        int idx = t + k * 256;                 // over 16 atoms x 64 ch
        int a = idx >> 6, c = idx & 63;
        int gi = blockIdx.x * 1024 + idx;
        int atom = blockIdx.x * 16 + a;
        float m = mask[atom];
        float v;
        if (UPD) {
            v = fmaxf(fmaf(s_buf[gi], affA[c], affB[c]) + emb[gi] * m, 0.f);
            emb[gi] = v;
        } else {
            v = emb[gi];
        }
        lexb[a][c] = (unsigned short)f2bf(v * m);
    }
    __syncthreads();
    const int lane = t & 63, w = t >> 6;
    const int l15 = lane & 15, lg = lane >> 4;
    // A-frags (k 0..31 / 32..63)
    const unsigned short* ap = &lexb[l15][lg * 8];
    union { uint4 u; bf16x8 v; } a0, a1;
    a0.u = *reinterpret_cast<const uint4*>(ap);
    a1.u = *reinterpret_cast<const uint4*>(ap + 32);
    // B-frags: f = h*16 + ks*8 + cb, cb in {w, w+4}
    union { uint4 u; bf16x8 v; } B[2][2][2];   // [h][cbi][ks]
#pragma unroll
    for (int h = 0; h < 2; ++h)
#pragma unroll
        for (int cbi = 0; cbi < 2; ++cbi)
#pragma unroll
            for (int ks = 0; ks < 2; ++ks)
                B[h][cbi][ks].u = wp[(h * 16 + ks * 8 + (w + cbi * 4)) * 64 + lane];
    float bias0 = fcb[w * 16 + l15];
    float bias4 = fcb[(w + 4) * 16 + l15];
    f32x4 aS0 = {bias0, bias0, bias0, bias0};
    f32x4 aS4 = {bias4, bias4, bias4, bias4};
    f32x4 aN0 = {0.f, 0.f, 0.f, 0.f};
    f32x4 aN4 = {0.f, 0.f, 0.f, 0.f};
    aS0 = __builtin_amdgcn_mfma_f32_16x16x32_bf16(a0.v, B[0][0][0].v, aS0, 0, 0, 0);
    aS0 = __builtin_amdgcn_mfma_f32_16x16x32_bf16(a1.v, B[0][0][1].v, aS0, 0, 0, 0);
    aS4 = __builtin_amdgcn_mfma_f32_16x16x32_bf16(a0.v, B[0][1][0].v, aS4, 0, 0, 0);
    aS4 = __builtin_amdgcn_mfma_f32_16x16x32_bf16(a1.v, B[0][1][1].v, aS4, 0, 0, 0);
    aN0 = __builtin_amdgcn_mfma_f32_16x16x32_bf16(a0.v, B[1][0][0].v, aN0, 0, 0, 0);
    aN0 = __builtin_amdgcn_mfma_f32_16x16x32_bf16(a1.v, B[1][0][1].v, aN0, 0, 0, 0);
    aN4 = __builtin_amdgcn_mfma_f32_16x16x32_bf16(a0.v, B[1][1][0].v, aN4, 0, 0, 0);
    aN4 = __builtin_amdgcn_mfma_f32_16x16x32_bf16(a1.v, B[1][1][1].v, aN4, 0, 0, 0);
    // stores: C row = atom-in-tile = lg*4+r, col = cb*16+l15
#pragma unroll
    for (int r = 0; r < 4; ++r) {
        size_t atomg = (size_t)blockIdx.x * 16 + lg * 4 + r;
        selfp[atomg * 128 + l15 * 8 + w] = aS0[r];
        selfp[atomg * 128 + l15 * 8 + w + 4] = aS4[r];
        uint32_t lo = (uint16_t)f2bf(aN0[r]);
        uint32_t hi = (uint16_t)f2bf(aN4[r]);
        nbrpU[atomg * 64 + l15 * 4 + w] = lo | (hi << 16);
    }
}

// ---------------- conv pass 1: z stats (MFMA e-term) -> atomic slots ---------------
__launch_bounds__(256, 4)
__global__ void k_conv_stats(const float* __restrict__ selfp, const uint32_t* __restrict__ nbrpU,
                             const uint4* __restrict__ pack, const int* __restrict__ adj,
                             const float* __restrict__ mask, const uint4* __restrict__ wpack,
                             float* __restrict__ slot1)
{
    __shared__ float red[4][256];
    const int lane = threadIdx.x & 63;
    const int wid = threadIdx.x >> 6;
    const int l15 = lane & 15, lg = lane >> 4;
    bf16x8 Wb[8];
#pragma unroll
    for (int cb = 0; cb < 8; ++cb) {
        union { uint4 u; bf16x8 v; } w;
        w.u = wpack[cb * 64 + lane];
        Wb[cb] = w.v;
    }
    float sum[8] = {0, 0, 0, 0, 0, 0, 0, 0};
    float sq[8] = {0, 0, 0, 0, 0, 0, 0, 0};
    const int wg = conv_wg(blockIdx.x);
    const int base = (wg * 4 + wid) * 4;
    const int adjv = adj[base * 16 + lane];    // all 4 atoms' neighbors in one load
    for (int aa = 0; aa < 4; ++aa) {
        const int bn = base + aa;
        const int b = bn >> 11;
        const float mn = mask[bn];
        union { uint4 u; bf16x8 v; } af;
        af.u = pack[(size_t)bn * 64 + lane];
        const float4* spp = reinterpret_cast<const float4*>(selfp + (size_t)bn * 128 + l15 * 8);
        float4 sA = spp[0], sB = spp[1];
        float sp[8] = {sA.x, sA.y, sA.z, sA.w, sB.x, sB.y, sB.z, sB.w};
        const uint32_t* npb = nbrpU + (size_t)b * NN * 64;
        f32x4 acc[8];
#pragma unroll
        for (int r = 0; r < 4; ++r) {
            const int am = __shfl(adjv, aa * 16 + lg * 4 + r);
            const uint4 u4 = *reinterpret_cast<const uint4*>(npb + (size_t)am * 64 + l15 * 4);
            acc[0][r] = fmaf(mn, bfLo(u4.x), sp[0]); acc[4][r] = fmaf(mn, bfHi(u4.x), sp[4]);
            acc[1][r] = fmaf(mn, bfLo(u4.y), sp[1]); acc[5][r] = fmaf(mn, bfHi(u4.y), sp[5]);
            acc[2][r] = fmaf(mn, bfLo(u4.z), sp[2]); acc[6][r] = fmaf(mn, bfHi(u4.z), sp[6]);
            acc[3][r] = fmaf(mn, bfLo(u4.w), sp[3]); acc[7][r] = fmaf(mn, bfHi(u4.w), sp[7]);
        }
#pragma unroll
        for (int cb = 0; cb < 8; ++cb)
            acc[cb] = __builtin_amdgcn_mfma_f32_16x16x32_bf16(af.v, Wb[cb], acc[cb], 0, 0, 0);
#pragma unroll
        for (int cb = 0; cb < 8; ++cb) {
#pragma unroll
            for (int r = 0; r < 4; ++r) {
                float z = acc[cb][r];
                sum[cb] += z; sq[cb] = fmaf(z, z, sq[cb]);
            }
        }
    }
#pragma unroll
    for (int cb = 0; cb < 8; ++cb) {
        sum[cb] += __shfl_xor(sum[cb], 16);
        sum[cb] += __shfl_xor(sum[cb], 32);
        sq[cb] += __shfl_xor(sq[cb], 16);
        sq[cb] += __shfl_xor(sq[cb], 32);
    }
    if (lane < 16) {
#pragma unroll
        for (int cb = 0; cb < 8; ++cb) {
            red[wid][cb * 16 + lane] = sum[cb];
            red[wid][128 + cb * 16 + lane] = sq[cb];
        }
    }
    __syncthreads();
    const int t = threadIdx.x;
    float v = red[0][t] + red[1][t] + red[2][t] + red[3][t];
    atomicAdd(&slot1[(blockIdx.x & (NSLOT - 1)) * 256 + t], v);
}

// ---------------- conv pass 2: BN1 finalize + gate + s stats -> atomic slots -------
__launch_bounds__(256, 4)
__global__ void k_conv_gate(const float* __restrict__ selfp, const uint32_t* __restrict__ nbrpU,
                            const uint4* __restrict__ pack, const int* __restrict__ adj,
                            const float* __restrict__ mask, const uint4* __restrict__ wpack,
                            const float* __restrict__ slot1,
                            const float* __restrict__ g0, const float* __restrict__ b0,
                            float* __restrict__ s_out, float* __restrict__ slot2)
{
    __shared__ float red[4][128];
    __shared__ float a1[128], b1s[128];
    const int t = threadIdx.x;
    if (t < 128) {
        float S = 0.f, Q = 0.f;
#pragma unroll
        for (int s = 0; s < NSLOT; ++s) {
            S += slot1[s * 256 + t];
            Q += slot1[s * 256 + 128 + t];
        }
        float mean = S * (1.f / 262144.f);
        float var = Q * (1.f / 262144.f) - mean * mean;
        float a = g0[t] * rsqrtf(var + EPS_);
        a1[t] = a; b1s[t] = b0[t] - mean * a;
    }
    __syncthreads();
    const int lane = threadIdx.x & 63;
    const int wid = threadIdx.x >> 6;
    const int l15 = lane & 15, lg = lane >> 4;
    bf16x8 Wb[8];
#pragma unroll
    for (int cb = 0; cb < 8; ++cb) {
        union { uint4 u; bf16x8 v; } w;
        w.u = wpack[cb * 64 + lane];
        Wb[cb] = w.v;
    }
    float aA[8], aB[8];
#pragma unroll
    for (int cb = 0; cb < 8; ++cb) {
        aA[cb] = a1[cb * 16 + l15];
        aB[cb] = b1s[cb * 16 + l15];
    }
    float ssum[4] = {0, 0, 0, 0}, ssq[4] = {0, 0, 0, 0};
    const int wg = conv_wg(blockIdx.x);
    const int base = (wg * 4 + wid) * 4;
    const int adjv = adj[base * 16 + lane];
    for (int aa = 0; aa < 4; ++aa) {
        const int bn = base + aa;
        const int b = bn >> 11;
        const float mn = mask[bn];
        union { uint4 u; bf16x8 v; } af;
        af.u = pack[(size_t)bn * 64 + lane];
        const float4* spp = reinterpret_cast<const float4*>(selfp + (size_t)bn * 128 + l15 * 8);
        float4 sA = spp[0], sB = spp[1];
        float sp[8] = {sA.x, sA.y, sA.z, sA.w, sB.x, sB.y, sB.z, sB.w};
        const uint32_t* npb = nbrpU + (size_t)b * NN * 64;
        f32x4 acc[8];
#pragma unroll
        for (int r = 0; r < 4; ++r) {
            const int am = __shfl(adjv, aa * 16 + lg * 4 + r);
            const uint4 u4 = *reinterpret_cast<const uint4*>(npb + (size_t)am * 64 + l15 * 4);
            acc[0][r] = fmaf(mn, bfLo(u4.x), sp[0]); acc[4][r] = fmaf(mn, bfHi(u4.x), sp[4]);
            acc[1][r] = fmaf(mn, bfLo(u4.y), sp[1]); acc[5][r] = fmaf(mn, bfHi(u4.y), sp[5]);
            acc[2][r] = fmaf(mn, bfLo(u4.z), sp[2]); acc[6][r] = fmaf(mn, bfHi(u4.z), sp[6]);
            acc[3][r] = fmaf(mn, bfLo(u4.w), sp[3]); acc[7][r] = fmaf(mn, bfHi(u4.w), sp[7]);
        }
#pragma unroll
        for (int cb = 0; cb < 8; ++cb)
            acc[cb] = __builtin_amdgcn_mfma_f32_16x16x32_bf16(af.v, Wb[cb], acc[cb], 0, 0, 0);
        float sv[4];
#pragma unroll
        for (int cb = 0; cb < 4; ++cb) {
            float s = 0.f;
#pragma unroll
            for (int r = 0; r < 4; ++r) {
                float zf = fmaf(acc[cb][r], aA[cb], aB[cb]);
                float zc = fmaf(acc[cb + 4][r], aA[cb + 4], aB[cb + 4]);
                float f = 1.f / (1.f + __expf(-zf));
                s = fmaf(f, fmaxf(zc, 0.f), s);
            }
            s += __shfl_xor(s, 16);
            s += __shfl_xor(s, 32);
            sv[cb] = s;
            ssum[cb] += s; ssq[cb] = fmaf(s, s, ssq[cb]);
        }
        if (lane < 16) {
#pragma unroll
            for (int cb = 0; cb < 4; ++cb)
                s_out[(size_t)bn * 64 + cb * 16 + lane] = sv[cb];
        }
    }
    if (lane < 16) {
#pragma unroll
        for (int cb = 0; cb < 4; ++cb) {
            red[wid][cb * 16 + lane] = ssum[cb];
            red[wid][64 + cb * 16 + lane] = ssq[cb];
        }
    }
    __syncthreads();
    if (t < 128) {
        float v = red[0][t] + red[1][t] + red[2][t] + red[3][t];
        atomicAdd(&slot2[(blockIdx.x & (NSLOT - 1)) * 128 + t], v);
    }
}

// ---------------- pooling (+ fused BN2 finalize & final update) ----------------
__launch_bounds__(256)
__global__ void k_pool(const float* __restrict__ emb, const float* __restrict__ s_buf,
                       const float* __restrict__ slot2,
                       const float* __restrict__ g1, const float* __restrict__ b1,
                       const float* __restrict__ mask, const int* __restrict__ aidx,
                       float* __restrict__ amino, float* __restrict__ psum,
                       float* __restrict__ msum, int* __restrict__ maxv)
{
    __shared__ float red[256];
    __shared__ float mred[4];
    __shared__ int kred[4];
    __shared__ float affA[64], affB[64];
    int t = threadIdx.x, sub = t >> 6, c = t & 63;
    if (t < 64) {
        float S = 0.f, Q = 0.f;
#pragma unroll
        for (int s = 0; s < NSLOT; ++s) {
            S += slot2[s * 128 + t];
            Q += slot2[s * 128 + 64 + t];
        }
        float mean = S * (1.f / 16384.f);
        float var = Q * (1.f / 16384.f) - mean * mean;
        float a = g1[t] * rsqrtf(var + EPS_);
        affA[t] = a; affB[t] = b1[t] - mean * a;
    }
    __syncthreads();
    int base = blockIdx.x * 32;
    int b = base >> 11;
    float pacc = 0.f, macc = 0.f;
    int kmax = 0;    // holds 0x7fffffff - kmin
    for (int j = 0; j < 8; ++j) {
        int bn = base + sub + 4 * j;
        size_t gi = (size_t)bn * 64 + c;
        float m = mask[bn];
        float e4 = fmaxf(fmaf(s_buf[gi], affA[c], affB[c]) + emb[gi] * m, 0.f);
        float v = e4 * m;
        int k = aidx[bn];
        atomicAdd(&amino[(size_t)k * 64 + c], v);
        pacc += v;
        if (c == 0) { macc += m; kmax = max(kmax, 0x7fffffff - k); }
    }
    red[t] = pacc;
    if (c == 0) { mred[sub] = macc; kred[sub] = kmax; }
    __syncthreads();
    if (t < 64) {
        float tot = red[t] + red[64 + t] + red[128 + t] + red[192 + t];
        atomicAdd(&psum[b * 64 + t], tot);
    }
    if (t == 0) {
        atomicAdd(&msum[b], mred[0] + mred[1] + mred[2] + mred[3]);
        atomicMax(maxv, max(max(kred[0], kred[1]), max(kred[2], kred[3])));
    }
}

// ---------------- heads: amino (blocks 0..255), protein (256), maskpooled (257..264) --
__launch_bounds__(256)
__global__ void k_heads(const float* __restrict__ amino, const float* __restrict__ W_af,
                        const float* __restrict__ b_af, const float* __restrict__ W_ao,
                        const float* __restrict__ b_ao,
                        const float* __restrict__ psum, const float* __restrict__ msum,
                        const float* __restrict__ W_cf, const float* __restrict__ b_cf,
                        const float* __restrict__ W_out, const float* __restrict__ b_out,
                        const int* __restrict__ maxv, float* __restrict__ out)
{
    const int t = threadIdx.x;
    if (blockIdx.x < 256) {
        int kk = t >> 5, j = t & 31;
        int k = blockIdx.x * 8 + kk;
        float acc = b_af[j];
        for (int c = 0; c < 64; ++c)
            acc = fmaf(fmaxf(amino[(size_t)k * 64 + c], 0.f), W_af[c * 32 + j], acc);
        float h = fmaxf(acc, 0.f);
        float val = h * W_ao[j];
        for (int off = 16; off > 0; off >>= 1) val += __shfl_down(val, off, 32);
        if (j == 0) out[8 + k] = val + b_ao[0];
    } else if (blockIdx.x == 256) {
        int bb = t >> 5, j = t & 31;
        float inv = 1.f / msum[bb];
        float acc = b_cf[j];
        for (int c = 0; c < 64; ++c)
            acc = fmaf(fmaxf(psum[bb * 64 + c] * inv, 0.f), W_cf[c * 32 + j], acc);
        float h = fmaxf(acc, 0.f);
        float val = h * W_out[j];
        for (int off = 16; off > 0; off >>= 1) val += __shfl_down(val, off, 32);
        if (j == 0) out[bb] = val + b_out[0];
    } else {
        int k = (blockIdx.x - 257) * 256 + t;
        int minv = 0x7fffffff - *maxv;
        out[8 + NAMINO_ + k] = (k < minv) ? 0.f : 1.f;
    }
}

// ---------------- launch ----------------
extern "C" void kernel_launch(void* const* d_in, const int* in_sizes, int n_in,
                              void* d_out, int out_size, void* d_ws, size_t ws_size,
                              hipStream_t stream)
{
    const int* atom_idx = (const int*)d_in[0];
    const float* nbr_emb = (const float*)d_in[1];
    const int* adj = (const int*)d_in[2];
    const int* aidx = (const int*)d_in[3];
    const float* mask = (const float*)d_in[4];
    const float* et = (const float*)d_in[5];
    const float* W_emb = (const float*)d_in[6];
    const float* b_emb = (const float*)d_in[7];
    const float* fcW = (const float*)d_in[8];
    const float* fcb = (const float*)d_in[9];
    const float* bnh_g = (const float*)d_in[10];
    const float* bnh_b = (const float*)d_in[11];
    const float* bno_g = (const float*)d_in[12];
    const float* bno_b = (const float*)d_in[13];
    const float* W_cf = (const float*)d_in[14];
    const float* b_cf = (const float*)d_in[15];
    const float* W_out = (const float*)d_in[16];
    const float* b_out = (const float*)d_in[17];
    const float* W_af = (const float*)d_in[18];
    const float* b_af = (const float*)d_in[19];
    const float* W_ao = (const float*)d_in[20];
    const float* b_ao = (const float*)d_in[21];

    float* ws = (float*)d_ws;
    float* emb = ws + OFF_EMB;
    float* selfp = ws + OFF_SELF;
    uint32_t* nbrpU = (uint32_t*)(ws + OFF_NBRU);
    float* s_buf = ws + OFF_S;
    float* amino = ws + OFF_AMINO;
    float* psum = ws + OFF_PSUM;
    float* msum = ws + OFF_MSUM;
    int* maxv = (int*)(ws + OFF_MAX);
    float* slot1 = ws + OFF_SLOT1;
    float* slot2 = ws + OFF_SLOT2;
    uint4* pack = (uint4*)(ws + OFF_PACK);
    uint4* wpack = (uint4*)(ws + OFF_WPACK);
    uint4* wpack2 = (uint4*)(ws + OFF_WPACK2);
    float* T = ws + OFF_T;
    float* out = (float*)d_out;

    // k_table also zeroes amino + psum + msum + maxv + all BN slots (blocks >= 25)
    k_table<<<25 + (ZERO_FLOATS + 255) / 256, 256, 0, stream>>>(et, W_emb, b_emb, T, amino);
    k_prep<<<5128, 256, 0, stream>>>(nbr_emb, pack, atom_idx, T, emb,
                                     fcW, wpack, wpack2);

    for (int i = 0; i < 4; ++i) {
        const uint4* wp2 = wpack2 + (size_t)i * 2048;
        if (i == 0)
            k_proj<0><<<NATOM / 16, 256, 0, stream>>>(emb, mask, s_buf, slot2, bno_g, bno_b,
                                                      wp2, fcb + i * 128, selfp, nbrpU);
        else
            k_proj<1><<<NATOM / 16, 256, 0, stream>>>(emb, mask, s_buf,
                                                      slot2 + (size_t)(i - 1) * (NSLOT * 128),
                                                      bno_g + (i - 1) * 64, bno_b + (i - 1) * 64,
                                                      wp2, fcb + i * 128, selfp, nbrpU);
        k_conv_stats<<<NPART, 256, 0, stream>>>(selfp, nbrpU, pack, adj, mask,
                                                wpack + (size_t)i * 512,
                                                slot1 + (size_t)i * (NSLOT * 256));
        k_conv_gate<<<NPART, 256, 0, stream>>>(selfp, nbrpU, pack, adj, mask,
                                               wpack + (size_t)i * 512,
                                               slot1 + (size_t)i * (NSLOT * 256),
                                               bnh_g + i * 128, bnh_b + i * 128,
                                               s_buf, slot2 + (size_t)i * (NSLOT * 128));
    }

    k_pool<<<NATOM / 32, 256, 0, stream>>>(emb, s_buf, slot2 + 3 * (NSLOT * 128),
                                           bno_g + 3 * 64, bno_b + 3 * 64,
                                           mask, aidx, amino, psum, msum, maxv);
    k_heads<<<265, 256, 0, stream>>>(amino, W_af, b_af, W_ao, b_ao,
                                     psum, msum, W_cf, b_cf, W_out, b_out, maxv, out);
}